// Round 5
// baseline (263.906 us; speedup 1.0000x reference)
//
#include <hip/hip_runtime.h>

// Problem constants (fixed by setup_inputs in the reference)
#define T_TABLES  8
#define N_TAB     2097152          // indices per table (2^21)
#define B_TAB     8192             // batch per table (2^13); offsets len = B_TAB+1
#define LOG2_NTAB 21
#define LOG2_B    13

#define TOTAL_IDX (T_TABLES * N_TAB)       // 16777216
#define N_OFF_OUT (T_TABLES * B_TAB + 1)   // 65537
#define WPB       2048                     // floats per window (2048 | 2^21 ->
                                           // every window lies in ONE table)
#define NBLK      2048                     // Guideline-11 grid: 2048 blocks
#define WIN_PER_BLK 4                      // 8192 windows / 2048 blocks

struct TablePtrs {
    const int*   idx[T_TABLES];
    const int*   off[T_TABLES];
    const float* wgt[T_TABLES];
};

typedef float __attribute__((ext_vector_type(4))) float4v;
typedef int   __attribute__((ext_vector_type(4))) int4v;

// ---------------------------------------------------------------------------
// Kernel 1: indices -> f32 copy-convert.
// 2048 blocks x 256 threads, 8 chunks (32 floats) per thread. Block window =
// 32 KiB, contiguous, in one table (8192 | 2^21). ALL 8 16B loads issued
// before any store -> deep per-wave VMEM queue; long-lived blocks avoid the
// 4x block-generation churn of the 8192-block config.
// ---------------------------------------------------------------------------
__global__ __launch_bounds__(256)
void tbe_idx_kernel(TablePtrs p, float* __restrict__ out) {
    const int i    = threadIdx.x;
    const int base = blockIdx.x * (WPB * WIN_PER_BLK);   // 8192 floats / block
    const int t    = base >> LOG2_NTAB;                  // one table per block
    const int j    = base & (N_TAB - 1);
    const int* __restrict__ src = p.idx[t] + j;
    float*     __restrict__ dst = out + base;

    int4v v[8];
#pragma unroll
    for (int k = 0; k < 8; ++k)
        v[k] = __builtin_nontemporal_load((const int4v*)(src + 4 * i + 1024 * k));

#pragma unroll
    for (int k = 0; k < 8; ++k) {
        float4v o;                                       // exact: vocab < 2^24
        o[0] = (float)v[k][0]; o[1] = (float)v[k][1];
        o[2] = (float)v[k][2]; o[3] = (float)v[k][3];
        __builtin_nontemporal_store(o, (float4v*)(dst + 4 * i + 1024 * k));
    }
}

// ---------------------------------------------------------------------------
// Kernel 2: weights copy (realigned via LDS) + rebased offsets.
// 2048 blocks x 4 windows of 2048 floats. All 8 16B loads issued up-front into
// 4x 8 KiB LDS buffers (32 KiB/block), ONE syncthreads, then dest-aligned 16B
// stores reading LDS at +3 floats (8-way bank conflict on an idle LDS pipe).
// ---------------------------------------------------------------------------
__global__ __launch_bounds__(256)
void tbe_wgt_kernel(TablePtrs p, float* __restrict__ out) {
    __shared__ float lds[WIN_PER_BLK][WPB];

    float* __restrict__ out_off = out + TOTAL_IDX;             // [.., +65537)
    float* __restrict__ out_w   = out + TOTAL_IDX + N_OFF_OUT; // [.., +16777216)
    // out_w begins at float index 16842753 (byte % 16 == 4): dest-aligned 16B
    // chunks within a window start at local float offset 3 + 4c.

    const int i   = threadIdx.x;
    const int tid = blockIdx.x * blockDim.x + i;               // < 524288

    // Issue ALL global weight loads up-front (8 x 16B in flight per thread).
    float4v wa[WIN_PER_BLK], wb[WIN_PER_BLK];
#pragma unroll
    for (int k = 0; k < WIN_PER_BLK; ++k) {
        const int D0 = (blockIdx.x * WIN_PER_BLK + k) * WPB;
        const int tw = D0 >> LOG2_NTAB;                  // window in one table
        const int jw = D0 & (N_TAB - 1);
        const float* __restrict__ wsrc = p.wgt[tw] + jw;
        wa[k] = __builtin_nontemporal_load((const float4v*)(wsrc + 4 * i));
        wb[k] = __builtin_nontemporal_load((const float4v*)(wsrc + 4 * (i + 256)));
    }

    // Region 3: rebased offsets (65537 scalar f32 stores; exact, max 2^24).
    // Overlaps with the weight loads' latency.
    if (tid < T_TABLES * B_TAB) {
        const int t = tid >> LOG2_B;
        const int k = tid & (B_TAB - 1);
        out_off[tid] = (float)(p.off[t][k] + t * N_TAB);
    } else if (tid == T_TABLES * B_TAB) {
        out_off[tid] = (float)TOTAL_IDX;   // grand total = 16777216 (exact in f32)
    }

    // Stage into LDS (contiguous b128 writes, conflict-free).
#pragma unroll
    for (int k = 0; k < WIN_PER_BLK; ++k) {
        *(float4v*)(&lds[k][4 * i])         = wa[k];
        *(float4v*)(&lds[k][4 * (i + 256)]) = wb[k];
    }

    __syncthreads();

    // Dest-aligned stores. Per window: 511 chunks cover [D0+3, D0+2047);
    // head 3 + tail 1 floats via scalar aligned dword stores (thread 255).
#pragma unroll
    for (int k = 0; k < WIN_PER_BLK; ++k) {
        const int D0 = (blockIdx.x * WIN_PER_BLK + k) * WPB;
        float* __restrict__ wdst = out_w + D0;
        {
            const int c = i;                              // c in [0, 256)
            float4v s;
            s[0] = lds[k][3 + 4 * c]; s[1] = lds[k][4 + 4 * c];
            s[2] = lds[k][5 + 4 * c]; s[3] = lds[k][6 + 4 * c];
            __builtin_nontemporal_store(s, (float4v*)(wdst + 3 + 4 * c));
        }
        if (i < 255) {
            const int c = i + 256;                        // c in [256, 511)
            float4v s;
            s[0] = lds[k][3 + 4 * c]; s[1] = lds[k][4 + 4 * c];
            s[2] = lds[k][5 + 4 * c]; s[3] = lds[k][6 + 4 * c];
            __builtin_nontemporal_store(s, (float4v*)(wdst + 3 + 4 * c));
        } else {
            wdst[0]       = lds[k][0];
            wdst[1]       = lds[k][1];
            wdst[2]       = lds[k][2];
            wdst[WPB - 1] = lds[k][WPB - 1];
        }
    }
}

extern "C" void kernel_launch(void* const* d_in, const int* in_sizes, int n_in,
                              void* d_out, int out_size, void* d_ws, size_t ws_size,
                              hipStream_t stream) {
    // setup_inputs() builds its dict INSIDE the per-table loop, so d_in is
    // interleaved triplets: [indices_0, offsets_0, weights_0, indices_1, ...].
    // Detect layout defensively via in_sizes (offsets are the only 8193-sized
    // inputs): interleaved -> in_sizes[1]==8193; grouped -> in_sizes[8]==8193.
    TablePtrs p;
    const bool interleaved = (n_in >= 2 && in_sizes[1] == B_TAB + 1);
    for (int i = 0; i < T_TABLES; ++i) {
        if (interleaved) {
            p.idx[i] = (const int*)  d_in[3 * i + 0];
            p.off[i] = (const int*)  d_in[3 * i + 1];
            p.wgt[i] = (const float*)d_in[3 * i + 2];
        } else {
            p.idx[i] = (const int*)  d_in[i];
            p.off[i] = (const int*)  d_in[T_TABLES + i];
            p.wgt[i] = (const float*)d_in[2 * T_TABLES + i];
        }
    }
    float* out = (float*)d_out;

    // Guideline-11 grid: 2048 long-lived blocks, 4x work per thread, deep
    // per-thread VMEM queues (8 x 16B loads in flight). Two phase-separated
    // dispatches (measured-free in round 4).
    dim3 grid(NBLK), block(256);
    hipLaunchKernelGGL(tbe_idx_kernel, grid, block, 0, stream, p, out);
    hipLaunchKernelGGL(tbe_wgt_kernel, grid, block, 0, stream, p, out);
}

// Round 6
// 259.631 us; speedup vs baseline: 1.0165x; 1.0165x over previous
//
#include <hip/hip_runtime.h>

// Problem constants (fixed by setup_inputs in the reference)
#define T_TABLES  8
#define N_TAB     2097152          // indices per table (2^21)
#define B_TAB     8192             // batch per table (2^13); offsets len = B_TAB+1
#define NV_TAB    (N_TAB / 4)      // 524288 = 2^19 vec4 chunks per table
#define LOG2_NV   19
#define LOG2_NTAB 21
#define LOG2_B    13

#define TOTAL_IDX (T_TABLES * N_TAB)       // 16777216
#define N_OFF_OUT (T_TABLES * B_TAB + 1)   // 65537
#define NTHREADS  2097152                  // 8192 blocks x 256 threads
#define WPB       2048                     // weight floats per block (2048 | 2^21
                                           // -> every block's range is in ONE table)

struct TablePtrs {
    const int*   idx[T_TABLES];
    const int*   off[T_TABLES];
    const float* wgt[T_TABLES];
};

typedef float __attribute__((ext_vector_type(4))) float4v;
typedef int   __attribute__((ext_vector_type(4))) int4v;

// Best-measured configuration (260.65 us, round 2 of this session).
// Tested-null levers (do NOT re-try without new counter evidence):
//   store alignment (straddle vs LDS-realign): ~2 us; store NT vs write-alloc: 0;
//   phase-split / stream topology: 0; 2048-deep-block granularity: -2.4 us.
// Kernel slice ~57 us vs ~43 us copy-roofline; residual is MALL dirty-drain
// contention from the preceding harness fill (outside kernel control).
__global__ __launch_bounds__(256)
void tbe_prep_kernel(TablePtrs p, float* __restrict__ out) {
    // 8 KiB staging buffer for the weights realignment (region 2).
    __shared__ float lds[WPB];

    float* __restrict__ out_idx = out;                         // [0, 16777216)
    float* __restrict__ out_off = out + TOTAL_IDX;             // [.., +65537)
    float* __restrict__ out_w   = out + TOTAL_IDX + N_OFF_OUT; // [.., +16777216)
    // out_w begins at float index 16842753 (byte % 16 == 4): dest-aligned 16B
    // chunks within a block's 2048-float window start at local offset 3 + 4c.

    const int tid = blockIdx.x * blockDim.x + threadIdx.x;
    const int i   = threadIdx.x;

    // ---- Issue ALL global loads unconditionally up-front (deep VMEM queue).
    // Region 1 (indices): both sides 16B-aligned, 2 chunks/thread.
    const int v0 = tid;
    const int v1 = tid + NTHREADS;
    const int t0 = v0 >> LOG2_NV, j0 = (v0 & (NV_TAB - 1)) << 2;
    const int t1 = v1 >> LOG2_NV, j1 = (v1 & (NV_TAB - 1)) << 2;
    const int4v ia = __builtin_nontemporal_load((const int4v*)(p.idx[t0] + j0));
    const int4v ib = __builtin_nontemporal_load((const int4v*)(p.idx[t1] + j1));

    // Region 2 (weights): block-local window [D0, D0+2048), source-ALIGNED loads.
    const int    D0   = blockIdx.x * WPB;
    const int    tw   = D0 >> LOG2_NTAB;        // whole block in one table
    const int    jw   = D0 & (N_TAB - 1);
    const float* wsrc = p.wgt[tw] + jw;
    const float4v wa = __builtin_nontemporal_load((const float4v*)(wsrc + 4 * i));
    const float4v wb = __builtin_nontemporal_load((const float4v*)(wsrc + 4 * (i + 256)));

    // Stage weights into LDS (contiguous b128 writes, conflict-free).
    *(float4v*)(lds + 4 * i)         = wa;
    *(float4v*)(lds + 4 * (i + 256)) = wb;

    // Region 1: int -> f32 (exact, vocab < 2^24), aligned streaming stores.
    float4v oa, ob;
    oa[0] = (float)ia[0]; oa[1] = (float)ia[1]; oa[2] = (float)ia[2]; oa[3] = (float)ia[3];
    ob[0] = (float)ib[0]; ob[1] = (float)ib[1]; ob[2] = (float)ib[2]; ob[3] = (float)ib[3];
    __builtin_nontemporal_store(oa, (float4v*)(out_idx + (v0 << 2)));
    __builtin_nontemporal_store(ob, (float4v*)(out_idx + (v1 << 2)));

    // Region 3: rebased offsets (65537 scalar f32 stores; exact, max 2^24).
    if (tid < T_TABLES * B_TAB) {
        const int t = tid >> LOG2_B;
        const int k = tid & (B_TAB - 1);
        out_off[tid] = (float)(p.off[t][k] + t * N_TAB);
    } else if (tid == T_TABLES * B_TAB) {
        out_off[tid] = (float)TOTAL_IDX;   // grand total = 16777216 (exact in f32)
    }

    __syncthreads();

    // Region 2 stores: read LDS shifted by +3 floats (8-way bank conflict on an
    // otherwise-idle LDS pipe), store dest-ALIGNED 16B chunks. 511 chunks cover
    // [D0+3, D0+2047); head 3 + tail 1 floats via scalar aligned dword stores.
    float* __restrict__ wdst = out_w + D0;
    {
        const int c = i;                                  // c in [0, 256)
        float4v s;
        s[0] = lds[3 + 4 * c]; s[1] = lds[4 + 4 * c];
        s[2] = lds[5 + 4 * c]; s[3] = lds[6 + 4 * c];
        __builtin_nontemporal_store(s, (float4v*)(wdst + 3 + 4 * c));
    }
    if (i < 255) {
        const int c = i + 256;                            // c in [256, 511)
        float4v s;
        s[0] = lds[3 + 4 * c]; s[1] = lds[4 + 4 * c];
        s[2] = lds[5 + 4 * c]; s[3] = lds[6 + 4 * c];
        __builtin_nontemporal_store(s, (float4v*)(wdst + 3 + 4 * c));
    } else {
        // i == 255: head (3 floats) + tail (1 float) of this block's window.
        wdst[0]       = lds[0];
        wdst[1]       = lds[1];
        wdst[2]       = lds[2];
        wdst[WPB - 1] = lds[WPB - 1];
    }
}

extern "C" void kernel_launch(void* const* d_in, const int* in_sizes, int n_in,
                              void* d_out, int out_size, void* d_ws, size_t ws_size,
                              hipStream_t stream) {
    // setup_inputs() builds its dict INSIDE the per-table loop, so d_in is
    // interleaved triplets: [indices_0, offsets_0, weights_0, indices_1, ...].
    // Detect layout defensively via in_sizes (offsets are the only 8193-sized
    // inputs): interleaved -> in_sizes[1]==8193; grouped -> in_sizes[8]==8193.
    TablePtrs p;
    const bool interleaved = (n_in >= 2 && in_sizes[1] == B_TAB + 1);
    for (int i = 0; i < T_TABLES; ++i) {
        if (interleaved) {
            p.idx[i] = (const int*)  d_in[3 * i + 0];
            p.off[i] = (const int*)  d_in[3 * i + 1];
            p.wgt[i] = (const float*)d_in[3 * i + 2];
        } else {
            p.idx[i] = (const int*)  d_in[i];
            p.off[i] = (const int*)  d_in[T_TABLES + i];
            p.wgt[i] = (const float*)d_in[2 * T_TABLES + i];
        }
    }
    float* out = (float*)d_out;

    // 8192 blocks x 256 threads: 2 idx chunks + 2 weight chunks per thread,
    // fully unrolled in-kernel. Pure-BW kernel; heavy oversubscription.
    dim3 grid(8192), block(256);
    hipLaunchKernelGGL(tbe_prep_kernel, grid, block, 0, stream, p, out);
}